// Round 10
// baseline (367.105 us; speedup 1.0000x reference)
//
#include <hip/hip_runtime.h>
#include <hip/hip_bf16.h>

typedef __attribute__((ext_vector_type(8))) short bf16x8;
typedef __attribute__((ext_vector_type(4))) float f32x4;

// ---------- helpers ----------
__device__ __forceinline__ unsigned short f2bf(float v) {
    union { __hip_bfloat16 h; unsigned short u; } cv;
    cv.h = __float2bfloat16(v);           // hw RNE convert
    return cv.u;
}
__device__ __forceinline__ float bf2f(unsigned short u) {
    return __uint_as_float(((unsigned int)u) << 16);
}
__device__ __forceinline__ float sigm(float x) { return 1.f / (1.f + __expf(-x)); }
__device__ __forceinline__ float tanh_(float x) { return 2.f / (1.f + __expf(-2.f * x)) - 1.f; }
__device__ __forceinline__ float adjW(int i, int j) {
    const float inv[8] = {1.f/4.f, 1.f/5.f, 1.f/6.f, 1.f/7.f,
                          1.f/7.f, 1.f/6.f, 1.f/5.f, 1.f/4.f};
    int d = i - j; d = d < 0 ? -d : d;
    return (d >= 1 && d <= 4) ? inv[i] : 0.f;
}

// =====================================================================
// K0: convert weights to bf16 in FRAGMENT-MAJOR layout (frag = 512 u16).
// elem (col,k) -> ((col>>4)*4 + (k>>5))*512 + ((k>>3)&3)*128 + (col&15)*8 + (k&7)
// u16 layout: [0 Wl12 2x16384][32768 Wr12 2x16384][65536 wih 2x49152]
//             [163840 whh 2x49152][262144 w0frag 4096 (K=4 zero-padded to 32)]
// =====================================================================
__global__ __launch_bounds__(256) void k0_wconv(const float* __restrict__ Wl12,
    const float* __restrict__ Wr12, const float* __restrict__ wih,
    const float* __restrict__ whh, const float* __restrict__ Wl0,
    const float* __restrict__ Wr0, unsigned short* __restrict__ wbf)
{
    int i = blockIdx.x * 256 + threadIdx.x;   // 0..266239
    if (i < 262144) {
        float v; int base, j;
        if (i < 32768)        { v = Wl12[i];        base = (i >> 14) * 16384;           j = i & 16383; }
        else if (i < 65536)   { int s = i - 32768;  v = Wr12[s]; base = 32768 + (s >> 14) * 16384; j = s & 16383; }
        else if (i < 163840)  { int s = i - 65536;  v = wih[s];  base = 65536 + (s / 49152) * 49152; j = s % 49152; }
        else                  { int s = i - 163840; v = whh[s];  base = 163840 + (s / 49152) * 49152; j = s % 49152; }
        int col = j >> 7, k = j & 127;
        int perm = ((col >> 4) * 4 + (k >> 5)) * 512 + ((k >> 3) & 3) * 128 + (col & 15) * 8 + (k & 7);
        wbf[base + perm] = f2bf(v);
    } else {
        // w0frag: combined [Wl0 | Wr0] at k=0..3, zero elsewhere
        int e2 = i - 262144;              // 0..4095
        int ct  = e2 >> 9;                // coltile 0..7
        int off = e2 & 511;
        int li2 = off >> 7;               // k>>3
        int rem = off & 127;
        int colLow = rem >> 3;
        int kLow = off & 7;
        int k = li2 * 8 + kLow;
        int col = ct * 16 + colLow;
        float v = 0.f;
        if (k < 2)      v = Wl0[col * 2 + k];
        else if (k < 4) v = Wr0[col * 2 + k - 2];
        wbf[i] = f2bf(v);
    }
}

// =====================================================================
// K1: fused graph stage, 256 thr (2 wr x 2 wc waves), 8 graphs/block.
// B-frags direct from L2. Residual h kept in C-frag REGISTERS (hPrev);
// layer-2 output never written to LDS; node-mean via shfl from regs.
// =====================================================================
__global__ __launch_bounds__(256, 3) void k1_sage(
    const float* __restrict__ iq,
    const float* __restrict__ bl0,
    const unsigned short* __restrict__ wbf,
    const float* __restrict__ bl12,
    const float* __restrict__ lng, const float* __restrict__ lnb,
    float* __restrict__ pf)
{
    __shared__ unsigned short hT[64 * 128];      // 16 KB h master, XOR-swizzled
    __shared__ float statS[64][4];
    __shared__ float xS[64][2], axS[64][2];

    const int t  = threadIdx.x;
    const int l  = t & 63;
    const int w  = t >> 6;
    const int wr = w >> 1, wc = w & 1;           // 2 x 2 waves
    const int lc = l & 15, li = l >> 4;
    const int kgrp = li * 8;
    const int half = li & 1;
    const int g0 = blockIdx.x * 8;

    // ---- patchify (8 graphs x 8 nodes x 2 ch = 128 items) ----
    if (t < 128) {
        int r = t >> 1, c = t & 1;
        int gid = g0 + (r >> 3);
        int node = r & 7;
        int b = gid / 31, p = gid - b * 31;
        xS[r][c] = iq[((size_t)b * 2 + c) * 128 + p * 4 + node];
    }
    __syncthreads();
    if (t < 128) {
        int r = t >> 1, c = t & 1;
        int node = r & 7, base = r & ~7;
        float s = 0.f;
        #pragma unroll
        for (int j = 0; j < 8; ++j) s += adjW(node, j) * xS[base + j][c];
        axS[r][c] = s;
    }
    __syncthreads();

    f32x4 acc[2][4];
    f32x4 hPrev[2][4];

    // LN epilogue: stats + normalize + relu (+residual in regs) -> hPrev,
    // optional hT write. bias must already be inside acc.
    auto ln_epi = [&](const float* gptr, const float* btptr, bool resid, bool writeHT) {
        float rs[2][4], rq[2][4];
        #pragma unroll
        for (int mt = 0; mt < 2; ++mt) {
            #pragma unroll
            for (int q = 0; q < 4; ++q) { rs[mt][q] = 0.f; rq[mt][q] = 0.f; }
            #pragma unroll
            for (int nt = 0; nt < 4; ++nt)
                #pragma unroll
                for (int q = 0; q < 4; ++q) {
                    float v = acc[mt][nt][q];
                    rs[mt][q] += v; rq[mt][q] += v * v;
                }
            #pragma unroll
            for (int q = 0; q < 4; ++q)
                #pragma unroll
                for (int m = 1; m < 16; m <<= 1) {
                    rs[mt][q] += __shfl_xor(rs[mt][q], m, 64);
                    rq[mt][q] += __shfl_xor(rq[mt][q], m, 64);
                }
        }
        if (lc == 0) {
            #pragma unroll
            for (int mt = 0; mt < 2; ++mt)
                #pragma unroll
                for (int q = 0; q < 4; ++q) {
                    int row = wr * 32 + mt * 16 + li * 4 + q;
                    statS[row][wc * 2]     = rs[mt][q];
                    statS[row][wc * 2 + 1] = rq[mt][q];
                }
        }
        __syncthreads();                 // statS ready
        float gam[4], bet[4];
        #pragma unroll
        for (int nt = 0; nt < 4; ++nt) {
            int col = wc * 64 + nt * 16 + lc;
            gam[nt] = gptr[col]; bet[nt] = btptr[col];
        }
        #pragma unroll
        for (int mt = 0; mt < 2; ++mt)
            #pragma unroll
            for (int q = 0; q < 4; ++q) {
                int row = wr * 32 + mt * 16 + li * 4 + q;
                int s8 = (row & 7) << 3;
                float4 st = *(const float4*)&statS[row][0];
                float sum = st.x + st.z, sq = st.y + st.w;
                float mu   = sum * (1.f / 128.f);
                float var  = sq * (1.f / 128.f) - mu * mu;
                float rstd = rsqrtf(var + 1e-5f);
                #pragma unroll
                for (int nt = 0; nt < 4; ++nt) {
                    int col = wc * 64 + nt * 16 + lc;
                    float v = (acc[mt][nt][q] - mu) * rstd * gam[nt] + bet[nt];
                    v = fmaxf(v, 0.f);
                    float hn = resid ? (hPrev[mt][nt][q] + v) : v;
                    hPrev[mt][nt][q] = hn;
                    if (writeHT) hT[row * 128 + (col ^ s8)] = f2bf(hn);
                }
            }
        if (writeHT) __syncthreads();    // hT(layer) complete before next hA load
    };

    // ---- layer 0 via MFMA: A = [agg_x | x] (K=4 in 32), B = w0frag ----
    {
        bf16x8 xA[2];
        #pragma unroll
        for (int mt = 0; mt < 2; ++mt) {
            bf16x8 v = (bf16x8){0, 0, 0, 0, 0, 0, 0, 0};
            if (li == 0) {
                int row = wr * 32 + mt * 16 + lc;
                v[0] = (short)f2bf(axS[row][0]); v[1] = (short)f2bf(axS[row][1]);
                v[2] = (short)f2bf(xS[row][0]);  v[3] = (short)f2bf(xS[row][1]);
            }
            xA[mt] = v;
        }
        const unsigned short* w0f = wbf + 262144;
        #pragma unroll
        for (int nt = 0; nt < 4; ++nt) {
            float bv = bl0[wc * 64 + nt * 16 + lc];
            acc[0][nt] = (f32x4){bv, bv, bv, bv};
            acc[1][nt] = (f32x4){bv, bv, bv, bv};
        }
        #pragma unroll
        for (int nt = 0; nt < 4; ++nt) {
            bf16x8 b0 = *(const bf16x8*)&w0f[(wc * 4 + nt) * 512 + l * 8];
            acc[0][nt] = __builtin_amdgcn_mfma_f32_16x16x32_bf16(xA[0], b0, acc[0][nt], 0, 0, 0);
            acc[1][nt] = __builtin_amdgcn_mfma_f32_16x16x32_bf16(xA[1], b0, acc[1][nt], 0, 0, 0);
        }
        ln_epi(lng, lnb, false, true);
    }

    // ---- layers 1,2 ----
    const int aswz = (lc & 7) << 3;     // A-frag row XOR (row&7 == lc&7)
    #pragma unroll 1
    for (int lay = 0; lay < 2; ++lay) {
        bf16x8 hA[2][4];
        #pragma unroll
        for (int mt = 0; mt < 2; ++mt)
            #pragma unroll
            for (int ks = 0; ks < 4; ++ks) {
                int row = wr * 32 + 16 * mt + lc;
                hA[mt][ks] = *(const bf16x8*)&hT[row * 128 + ((ks * 32 + kgrp) ^ aswz)];
            }

        const unsigned short* wl  = wbf + lay * 16384;            // frag-major
        const unsigned short* wrp = wbf + 32768 + lay * 16384;

        #pragma unroll
        for (int mt = 0; mt < 2; ++mt)
            #pragma unroll
            for (int nt = 0; nt < 4; ++nt) acc[mt][nt] = (f32x4){0.f, 0.f, 0.f, 0.f};

        // pass 1: Y1 = h @ Wl^T  (B from L2)
        #pragma unroll
        for (int ks = 0; ks < 4; ++ks) {
            #pragma unroll
            for (int nt = 0; nt < 4; ++nt) {
                bf16x8 b = *(const bf16x8*)&wl[((wc * 4 + nt) * 4 + ks) * 512 + l * 8];
                acc[0][nt] = __builtin_amdgcn_mfma_f32_16x16x32_bf16(hA[0][ks], b, acc[0][nt], 0, 0, 0);
                acc[1][nt] = __builtin_amdgcn_mfma_f32_16x16x32_bf16(hA[1][ks], b, acc[1][nt], 0, 0, 0);
            }
        }

        // A-apply in C-frag regs (verified)
        #pragma unroll
        for (int mt = 0; mt < 2; ++mt)
            #pragma unroll
            for (int nt = 0; nt < 4; ++nt) {
                float own[4], oth[4];
                #pragma unroll
                for (int q = 0; q < 4; ++q) {
                    own[q] = acc[mt][nt][q];
                    oth[q] = __shfl_xor(own[q], 16, 64);
                }
                float yL[4], yH[4];
                #pragma unroll
                for (int q = 0; q < 4; ++q) {
                    yL[q] = half ? oth[q] : own[q];
                    yH[q] = half ? own[q] : oth[q];
                }
                float S = yL[0]+yL[1]+yL[2]+yL[3]+yH[0]+yH[1]+yH[2]+yH[3];
                float o0, o1, o2, o3;
                if (!half) {
                    o0 = (S - yL[0] - yH[1] - yH[2] - yH[3]) * 0.25f;
                    o1 = (S - yL[1] - yH[2] - yH[3]) * 0.2f;
                    o2 = (S - yL[2] - yH[3]) * (1.f/6.f);
                    o3 = (S - yL[3]) * (1.f/7.f);
                } else {
                    o0 = (S - yH[0]) * (1.f/7.f);
                    o1 = (S - yH[1] - yL[0]) * (1.f/6.f);
                    o2 = (S - yH[2] - yL[0] - yL[1]) * 0.2f;
                    o3 = (S - yH[3] - yL[0] - yL[1] - yL[2]) * 0.25f;
                }
                acc[mt][nt][0] = o0; acc[mt][nt][1] = o1;
                acc[mt][nt][2] = o2; acc[mt][nt][3] = o3;
            }

        // add bias (after A-apply, before pass-2 accumulation)
        #pragma unroll
        for (int nt = 0; nt < 4; ++nt) {
            float bv = bl12[lay * 128 + wc * 64 + nt * 16 + lc];
            #pragma unroll
            for (int mt = 0; mt < 2; ++mt)
                #pragma unroll
                for (int q = 0; q < 4; ++q) acc[mt][nt][q] += bv;
        }

        // pass 2: acc += h @ Wr^T  (B from L2)
        #pragma unroll
        for (int ks = 0; ks < 4; ++ks) {
            #pragma unroll
            for (int nt = 0; nt < 4; ++nt) {
                bf16x8 b = *(const bf16x8*)&wrp[((wc * 4 + nt) * 4 + ks) * 512 + l * 8];
                acc[0][nt] = __builtin_amdgcn_mfma_f32_16x16x32_bf16(hA[0][ks], b, acc[0][nt], 0, 0, 0);
                acc[1][nt] = __builtin_amdgcn_mfma_f32_16x16x32_bf16(hA[1][ks], b, acc[1][nt], 0, 0, 0);
            }
        }

        // layer1 (lay=0): write hT for next layer's A-frags.
        // layer2 (lay=1): keep result only in hPrev regs.
        ln_epi(lng + (lay + 1) * 128, lnb + (lay + 1) * 128, true, lay == 0);
    }

    // ---- node mean from hPrev regs -> patch features ----
    // tile mt rows: R=wr*32+mt*16; li<2 holds rows R..R+7 (graph R/8),
    // li>=2 holds rows R+8..R+15 (graph R/8+1). shfl_xor(16) merges li pairs.
    #pragma unroll
    for (int mt = 0; mt < 2; ++mt) {
        #pragma unroll
        for (int nt = 0; nt < 4; ++nt) {
            float s = hPrev[mt][nt][0] + hPrev[mt][nt][1]
                    + hPrev[mt][nt][2] + hPrev[mt][nt][3];
            s += __shfl_xor(s, 16, 64);
            if ((li & 1) == 0) {
                int gi = wr * 4 + mt * 2 + (li >> 1);
                pf[(size_t)(g0 + gi) * 128 + wc * 64 + nt * 16 + lc] = s * 0.125f;
            }
        }
    }
}

// =====================================================================
// K2: xg1 = pf(63488,128) @ wih1^T + bih1 -> bf16. wB frag-major (stride 512).
// =====================================================================
__global__ __launch_bounds__(256) void k2_xg(
    const float* __restrict__ src, const unsigned short* __restrict__ wB,
    const float* __restrict__ bias, unsigned short* __restrict__ out)
{
    const int t = threadIdx.x, w = t >> 6, l = t & 63;
    const int lc = l & 15, li = l >> 4;
    const int m0 = blockIdx.x * 64 + w * 16;

    bf16x8 aA[4];
    #pragma unroll
    for (int ks = 0; ks < 4; ++ks) {
        const float* p = src + (size_t)(m0 + lc) * 128 + ks * 32 + li * 8;
        float4 f0 = *(const float4*)p;
        float4 f1 = *(const float4*)(p + 4);
        bf16x8 v;
        v[0] = (short)f2bf(f0.x); v[1] = (short)f2bf(f0.y);
        v[2] = (short)f2bf(f0.z); v[3] = (short)f2bf(f0.w);
        v[4] = (short)f2bf(f1.x); v[5] = (short)f2bf(f1.y);
        v[6] = (short)f2bf(f1.z); v[7] = (short)f2bf(f1.w);
        aA[ks] = v;
    }
    #pragma unroll 2
    for (int nt = 0; nt < 24; ++nt) {
        float bv = bias[nt * 16 + lc];
        f32x4 acc = (f32x4){bv, bv, bv, bv};
        #pragma unroll
        for (int ks = 0; ks < 4; ++ks) {
            bf16x8 b = *(const bf16x8*)&wB[(size_t)(nt * 4 + ks) * 512 + l * 8];
            acc = __builtin_amdgcn_mfma_f32_16x16x32_bf16(aA[ks], b, acc, 0, 0, 0);
        }
        #pragma unroll
        for (int q = 0; q < 4; ++q) {
            int m = m0 + li * 4 + q;
            out[(size_t)m * 384 + nt * 16 + lc] = f2bf(acc[q]);
        }
    }
}

// =====================================================================
// K3: both GRU layers fused, 31 steps in-kernel, weights (frag-major) in regs.
// =====================================================================
__global__ __launch_bounds__(512, 2) void k3_gru(
    const unsigned short* __restrict__ xg, const unsigned short* __restrict__ wbf,
    const float* __restrict__ bih, const float* __restrict__ bhh,
    float* __restrict__ gbuf)
{
    __shared__ unsigned short h1S[16][136];
    __shared__ unsigned short h2S[16][136];

    const int t = threadIdx.x, w = t >> 6, l = t & 63;
    const int lc = l & 15, li = l >> 4;
    const int col = w * 16 + lc;          // 0..127
    const int kgrp = li * 8;
    const int b0 = blockIdx.x * 8;
    const bool act = (li < 2);

    for (int i = t; i < 16 * 136; i += 512) {
        ((unsigned short*)h1S)[i] = 0;
        ((unsigned short*)h2S)[i] = 0;
    }

    const unsigned short* wih2 = wbf + 114688;
    const unsigned short* whh1 = wbf + 163840;
    const unsigned short* whh2 = wbf + 212992;
    bf16x8 Wh1[3][4], Wi2[3][4], Wh2[3][4];
    #pragma unroll
    for (int g = 0; g < 3; ++g)
        #pragma unroll
        for (int ks = 0; ks < 4; ++ks) {
            size_t off = (size_t)((g * 8 + w) * 4 + ks) * 512 + l * 8;
            Wh1[g][ks] = *(const bf16x8*)(whh1 + off);
            Wi2[g][ks] = *(const bf16x8*)(wih2 + off);
            Wh2[g][ks] = *(const bf16x8*)(whh2 + off);
        }
    float bh1[3], bi2[3], bh2[3];
    #pragma unroll
    for (int g = 0; g < 3; ++g) {
        bh1[g] = bhh[g * 128 + col];
        bi2[g] = bih[384 + g * 128 + col];
        bh2[g] = bhh[384 + g * 128 + col];
    }

    float h1r[4] = {0.f, 0.f, 0.f, 0.f};
    float h2r[4] = {0.f, 0.f, 0.f, 0.f};
    float x1[3][4];

    if (act) {
        #pragma unroll
        for (int g = 0; g < 3; ++g)
            #pragma unroll
            for (int q = 0; q < 4; ++q)
                x1[g][q] = bf2f(xg[((size_t)(b0 + li * 4 + q) * 31 + 0) * 384 + g * 128 + col]);
    }
    __syncthreads();

    for (int ts = 0; ts < 31; ++ts) {
        bf16x8 aH[4];
        #pragma unroll
        for (int ks = 0; ks < 4; ++ks) aH[ks] = *(const bf16x8*)&h1S[lc][ks * 32 + kgrp];
        f32x4 acc[3];
        #pragma unroll
        for (int g = 0; g < 3; ++g) {
            acc[g] = (f32x4){0.f, 0.f, 0.f, 0.f};
            #pragma unroll
            for (int ks = 0; ks < 4; ++ks)
                acc[g] = __builtin_amdgcn_mfma_f32_16x16x32_bf16(aH[ks], Wh1[g][ks], acc[g], 0, 0, 0);
        }
        float xn[3][4];
        if (act && ts < 30) {
            #pragma unroll
            for (int g = 0; g < 3; ++g)
                #pragma unroll
                for (int q = 0; q < 4; ++q)
                    xn[g][q] = bf2f(xg[((size_t)(b0 + li * 4 + q) * 31 + ts + 1) * 384 + g * 128 + col]);
        }
        if (act) {
            #pragma unroll
            for (int q = 0; q < 4; ++q) {
                float r  = sigm(x1[0][q] + acc[0][q] + bh1[0]);
                float z  = sigm(x1[1][q] + acc[1][q] + bh1[1]);
                float nn = tanh_(x1[2][q] + r * (acc[2][q] + bh1[2]));
                h1r[q] = (1.f - z) * nn + z * h1r[q];
            }
        }
        __syncthreads();
        if (act) {
            #pragma unroll
            for (int q = 0; q < 4; ++q) h1S[li * 4 + q][col] = f2bf(h1r[q]);
        }
        __syncthreads();

        bf16x8 aH1n[4], aH2[4];
        #pragma unroll
        for (int ks = 0; ks < 4; ++ks) {
            aH1n[ks] = *(const bf16x8*)&h1S[lc][ks * 32 + kgrp];
            aH2[ks]  = *(const bf16x8*)&h2S[lc][ks * 32 + kgrp];
        }
        f32x4 ax2[3], ah2[3];
        #pragma unroll
        for (int g = 0; g < 3; ++g) {
            ax2[g] = (f32x4){0.f, 0.f, 0.f, 0.f};
            ah2[g] = (f32x4){0.f, 0.f, 0.f, 0.f};
            #pragma unroll
            for (int ks = 0; ks < 4; ++ks) {
                ax2[g] = __builtin_amdgcn_mfma_f32_16x16x32_bf16(aH1n[ks], Wi2[g][ks], ax2[g], 0, 0, 0);
                ah2[g] = __builtin_amdgcn_mfma_f32_16x16x32_bf16(aH2[ks],  Wh2[g][ks], ah2[g], 0, 0, 0);
            }
        }
        if (act) {
            #pragma unroll
            for (int q = 0; q < 4; ++q) {
                float xr = ax2[0][q] + bi2[0];
                float xz = ax2[1][q] + bi2[1];
                float xn2 = ax2[2][q] + bi2[2];
                float r  = sigm(xr + ah2[0][q] + bh2[0]);
                float z  = sigm(xz + ah2[1][q] + bh2[1]);
                float nn = tanh_(xn2 + r * (ah2[2][q] + bh2[2]));
                h2r[q] = (1.f - z) * nn + z * h2r[q];
            }
        }
        __syncthreads();
        if (act) {
            #pragma unroll
            for (int q = 0; q < 4; ++q) h2S[li * 4 + q][col] = f2bf(h2r[q]);
        }
        __syncthreads();

        #pragma unroll
        for (int g = 0; g < 3; ++g)
            #pragma unroll
            for (int q = 0; q < 4; ++q) x1[g][q] = xn[g][q];
    }

    if (act) {
        #pragma unroll
        for (int q = 0; q < 4; ++q)
            gbuf[(size_t)(b0 + li * 4 + q) * 128 + col] = h2r[q];
    }
}

// =====================================================================
// K4: logits = g(2048,128) @ etf(128,8)
// =====================================================================
__global__ __launch_bounds__(256) void k4_logits(
    const float* __restrict__ g, const float* __restrict__ etf, float* __restrict__ logits)
{
    const int idx = blockIdx.x * 256 + threadIdx.x;
    const int b = idx >> 3, c = idx & 7;
    float s = 0.f;
    #pragma unroll 8
    for (int f = 0; f < 128; ++f) s += g[(size_t)b * 128 + f] * etf[f * 8 + c];
    logits[idx] = s;
}

// =====================================================================
extern "C" void kernel_launch(void* const* d_in, const int* in_sizes, int n_in,
                              void* d_out, int out_size, void* d_ws, size_t ws_size,
                              hipStream_t stream) {
    const float* iq   = (const float*)d_in[0];
    const float* Wl0  = (const float*)d_in[1];
    const float* bl0  = (const float*)d_in[2];
    const float* Wr0  = (const float*)d_in[3];
    const float* Wl12 = (const float*)d_in[4];
    const float* bl12 = (const float*)d_in[5];
    const float* Wr12 = (const float*)d_in[6];
    const float* lng  = (const float*)d_in[7];
    const float* lnb  = (const float*)d_in[8];
    const float* wih  = (const float*)d_in[9];
    const float* whh  = (const float*)d_in[10];
    const float* bih  = (const float*)d_in[11];
    const float* bhh  = (const float*)d_in[12];
    const float* etf  = (const float*)d_in[13];

    float* out    = (float*)d_out;
    float* logits = out;                       // 2048*8
    float* gbuf   = out + 16384;               // 2048*128
    float* pf     = out + 16384 + 262144;      // 63488*128

    // ws: [wbf 266240 u16 = 520KB][xg1 bf16 63488*384 u16 = 48.76MB]
    unsigned short* wbf = (unsigned short*)d_ws;
    unsigned short* xg  = wbf + 266240;

    k0_wconv<<<1040, 256, 0, stream>>>(Wl12, Wr12, wih, whh, Wl0, Wr0, wbf);
    k1_sage<<<7936, 256, 0, stream>>>(iq, bl0, wbf, bl12, lng, lnb, pf);
    k2_xg<<<992, 256, 0, stream>>>(pf, wbf + 65536, bih, xg);
    k3_gru<<<256, 512, 0, stream>>>(xg, wbf, bih, bhh, gbuf);
    k4_logits<<<64, 256, 0, stream>>>(gbuf, etf, logits);
}

// Round 11
// 311.122 us; speedup vs baseline: 1.1799x; 1.1799x over previous
//
#include <hip/hip_runtime.h>
#include <hip/hip_bf16.h>

typedef __attribute__((ext_vector_type(8))) short bf16x8;
typedef __attribute__((ext_vector_type(4))) float f32x4;

// ---------- helpers ----------
__device__ __forceinline__ unsigned short f2bf(float v) {
    union { __hip_bfloat16 h; unsigned short u; } cv;
    cv.h = __float2bfloat16(v);           // hw RNE convert
    return cv.u;
}
__device__ __forceinline__ float bf2f(unsigned short u) {
    return __uint_as_float(((unsigned int)u) << 16);
}
__device__ __forceinline__ float sigm(float x) { return 1.f / (1.f + __expf(-x)); }
__device__ __forceinline__ float tanh_(float x) { return 2.f / (1.f + __expf(-2.f * x)) - 1.f; }
__device__ __forceinline__ float adjW(int i, int j) {
    const float inv[8] = {1.f/4.f, 1.f/5.f, 1.f/6.f, 1.f/7.f,
                          1.f/7.f, 1.f/6.f, 1.f/5.f, 1.f/4.f};
    int d = i - j; d = d < 0 ? -d : d;
    return (d >= 1 && d <= 4) ? inv[i] : 0.f;
}

// DPP 16-lane row reduction (VALU pipe, ~2cy/step — replaces ds_swizzle shfls)
template<int CTRL>
__device__ __forceinline__ float dppadd(float v) {
    int d = __builtin_amdgcn_update_dpp(0, __float_as_int(v), CTRL, 0xF, 0xF, true);
    return v + __int_as_float(d);
}
__device__ __forceinline__ float rowsum16(float v) {
    v = dppadd<0xB1>(v);    // quad_perm(1,0,3,2)  == xor 1
    v = dppadd<0x4E>(v);    // quad_perm(2,3,0,1)  == xor 2
    v = dppadd<0x124>(v);   // row_ror:4
    v = dppadd<0x128>(v);   // row_ror:8
    return v;
}

// =====================================================================
// K0: convert weights to bf16 in FRAGMENT-MAJOR layout (frag = 512 u16).
// elem (col,k) -> ((col>>4)*4 + (k>>5))*512 + ((k>>3)&3)*128 + (col&15)*8 + (k&7)
// u16 layout: [0 Wl12 2x16384][32768 Wr12 2x16384][65536 wih 2x49152]
//             [163840 whh 2x49152][262144 w0frag 4096 (K=4 zero-padded to 32)]
// =====================================================================
__global__ __launch_bounds__(256) void k0_wconv(const float* __restrict__ Wl12,
    const float* __restrict__ Wr12, const float* __restrict__ wih,
    const float* __restrict__ whh, const float* __restrict__ Wl0,
    const float* __restrict__ Wr0, unsigned short* __restrict__ wbf)
{
    int i = blockIdx.x * 256 + threadIdx.x;   // 0..266239
    if (i < 262144) {
        float v; int base, j;
        if (i < 32768)        { v = Wl12[i];        base = (i >> 14) * 16384;           j = i & 16383; }
        else if (i < 65536)   { int s = i - 32768;  v = Wr12[s]; base = 32768 + (s >> 14) * 16384; j = s & 16383; }
        else if (i < 163840)  { int s = i - 65536;  v = wih[s];  base = 65536 + (s / 49152) * 49152; j = s % 49152; }
        else                  { int s = i - 163840; v = whh[s];  base = 163840 + (s / 49152) * 49152; j = s % 49152; }
        int col = j >> 7, k = j & 127;
        int perm = ((col >> 4) * 4 + (k >> 5)) * 512 + ((k >> 3) & 3) * 128 + (col & 15) * 8 + (k & 7);
        wbf[base + perm] = f2bf(v);
    } else {
        // w0frag: combined [Wl0 | Wr0] at k=0..3, zero elsewhere
        int e2 = i - 262144;              // 0..4095
        int ct  = e2 >> 9;                // coltile 0..7
        int off = e2 & 511;
        int li2 = off >> 7;               // k>>3
        int rem = off & 127;
        int colLow = rem >> 3;
        int kLow = off & 7;
        int k = li2 * 8 + kLow;
        int col = ct * 16 + colLow;
        float v = 0.f;
        if (k < 2)      v = Wl0[col * 2 + k];
        else if (k < 4) v = Wr0[col * 2 + k - 2];
        wbf[i] = f2bf(v);
    }
}

// =====================================================================
// K1: fused graph stage, 256 thr (2 wr x 2 wc waves), 8 graphs/block.
// B-frags read DIRECTLY from L2 (frag-major, 1KB/wave contiguous).
// No weight LDS. hT bf16 XOR-swizzled. Bias folded into acc init.
// LN stats via DPP row reduction (VALU) — DS pipe only for A-frags/statS/hT.
// =====================================================================
__global__ __launch_bounds__(256, 4) void k1_sage(
    const float* __restrict__ iq,
    const float* __restrict__ bl0,
    const unsigned short* __restrict__ wbf,
    const float* __restrict__ bl12,
    const float* __restrict__ lng, const float* __restrict__ lnb,
    float* __restrict__ pf)
{
    __shared__ unsigned short hT[64 * 128];      // 16 KB h master, XOR-swizzled
    __shared__ float statS[64][4];
    __shared__ float xS[64][2], axS[64][2];

    const int t  = threadIdx.x;
    const int l  = t & 63;
    const int w  = t >> 6;
    const int wr = w >> 1, wc = w & 1;           // 2 x 2 waves
    const int lc = l & 15, li = l >> 4;
    const int kgrp = li * 8;
    const int half = li & 1;
    const int g0 = blockIdx.x * 8;

    // ---- patchify (8 graphs x 8 nodes x 2 ch = 128 items) ----
    if (t < 128) {
        int r = t >> 1, c = t & 1;
        int gid = g0 + (r >> 3);
        int node = r & 7;
        int b = gid / 31, p = gid - b * 31;
        xS[r][c] = iq[((size_t)b * 2 + c) * 128 + p * 4 + node];
    }
    __syncthreads();
    if (t < 128) {
        int r = t >> 1, c = t & 1;
        int node = r & 7, base = r & ~7;
        float s = 0.f;
        #pragma unroll
        for (int j = 0; j < 8; ++j) s += adjW(node, j) * xS[base + j][c];
        axS[r][c] = s;
    }
    __syncthreads();

    f32x4 acc[2][4];

    // shared LN epilogue: stats (DPP) + normalize(+relu)(+residual RMW) -> hT
    // (bias already inside acc)
    auto ln_epi = [&](const float* gptr, const float* btptr, bool resid) {
        float rs[2][4], rq[2][4];
        #pragma unroll
        for (int mt = 0; mt < 2; ++mt) {
            #pragma unroll
            for (int q = 0; q < 4; ++q) { rs[mt][q] = 0.f; rq[mt][q] = 0.f; }
            #pragma unroll
            for (int nt = 0; nt < 4; ++nt)
                #pragma unroll
                for (int q = 0; q < 4; ++q) {
                    float v = acc[mt][nt][q];
                    rs[mt][q] += v; rq[mt][q] += v * v;
                }
            #pragma unroll
            for (int q = 0; q < 4; ++q) {
                rs[mt][q] = rowsum16(rs[mt][q]);
                rq[mt][q] = rowsum16(rq[mt][q]);
            }
        }
        if (lc == 0) {
            #pragma unroll
            for (int mt = 0; mt < 2; ++mt)
                #pragma unroll
                for (int q = 0; q < 4; ++q) {
                    int row = wr * 32 + mt * 16 + li * 4 + q;
                    statS[row][wc * 2]     = rs[mt][q];
                    statS[row][wc * 2 + 1] = rq[mt][q];
                }
        }
        __syncthreads();                 // statS ready
        float gam[4], bet[4];
        #pragma unroll
        for (int nt = 0; nt < 4; ++nt) {
            int col = wc * 64 + nt * 16 + lc;
            gam[nt] = gptr[col]; bet[nt] = btptr[col];
        }
        #pragma unroll
        for (int mt = 0; mt < 2; ++mt)
            #pragma unroll
            for (int q = 0; q < 4; ++q) {
                int row = wr * 32 + mt * 16 + li * 4 + q;
                int s8 = (row & 7) << 3;
                float4 st = *(const float4*)&statS[row][0];
                float sum = st.x + st.z, sq = st.y + st.w;
                float mu   = sum * (1.f / 128.f);
                float var  = sq * (1.f / 128.f) - mu * mu;
                float rstd = rsqrtf(var + 1e-5f);
                #pragma unroll
                for (int nt = 0; nt < 4; ++nt) {
                    int col = wc * 64 + nt * 16 + lc;
                    int idx = row * 128 + (col ^ s8);
                    float v = (acc[mt][nt][q] - mu) * rstd * gam[nt] + bet[nt];
                    v = fmaxf(v, 0.f);
                    float hn = resid ? (bf2f(hT[idx]) + v) : v;
                    hT[idx] = f2bf(hn);
                }
            }
        __syncthreads();                 // hT(layer) complete
    };

    // ---- layer 0 via MFMA: A = [agg_x | x] (K=4 in 32), B = w0frag ----
    {
        bf16x8 xA[2];
        #pragma unroll
        for (int mt = 0; mt < 2; ++mt) {
            bf16x8 v = (bf16x8){0, 0, 0, 0, 0, 0, 0, 0};
            if (li == 0) {
                int row = wr * 32 + mt * 16 + lc;
                v[0] = (short)f2bf(axS[row][0]); v[1] = (short)f2bf(axS[row][1]);
                v[2] = (short)f2bf(xS[row][0]);  v[3] = (short)f2bf(xS[row][1]);
            }
            xA[mt] = v;
        }
        const unsigned short* w0f = wbf + 262144;
        #pragma unroll
        for (int nt = 0; nt < 4; ++nt) {
            float bv = bl0[wc * 64 + nt * 16 + lc];
            acc[0][nt] = (f32x4){bv, bv, bv, bv};
            acc[1][nt] = (f32x4){bv, bv, bv, bv};
        }
        #pragma unroll
        for (int nt = 0; nt < 4; ++nt) {
            bf16x8 b0 = *(const bf16x8*)&w0f[(wc * 4 + nt) * 512 + l * 8];
            acc[0][nt] = __builtin_amdgcn_mfma_f32_16x16x32_bf16(xA[0], b0, acc[0][nt], 0, 0, 0);
            acc[1][nt] = __builtin_amdgcn_mfma_f32_16x16x32_bf16(xA[1], b0, acc[1][nt], 0, 0, 0);
        }
        ln_epi(lng, lnb, false);
    }

    // ---- layers 1,2 ----
    const int aswz = (lc & 7) << 3;     // A-frag row XOR (row&7 == lc&7)
    #pragma unroll 1
    for (int lay = 0; lay < 2; ++lay) {
        bf16x8 hA[2][4];
        #pragma unroll
        for (int mt = 0; mt < 2; ++mt)
            #pragma unroll
            for (int ks = 0; ks < 4; ++ks) {
                int row = wr * 32 + 16 * mt + lc;
                hA[mt][ks] = *(const bf16x8*)&hT[row * 128 + ((ks * 32 + kgrp) ^ aswz)];
            }

        const unsigned short* wl  = wbf + lay * 16384;            // frag-major
        const unsigned short* wrp = wbf + 32768 + lay * 16384;

        #pragma unroll
        for (int mt = 0; mt < 2; ++mt)
            #pragma unroll
            for (int nt = 0; nt < 4; ++nt) acc[mt][nt] = (f32x4){0.f, 0.f, 0.f, 0.f};

        // pass 1: Y1 = h @ Wl^T  (B from L2)
        #pragma unroll
        for (int ks = 0; ks < 4; ++ks) {
            #pragma unroll
            for (int nt = 0; nt < 4; ++nt) {
                bf16x8 b = *(const bf16x8*)&wl[((wc * 4 + nt) * 4 + ks) * 512 + l * 8];
                acc[0][nt] = __builtin_amdgcn_mfma_f32_16x16x32_bf16(hA[0][ks], b, acc[0][nt], 0, 0, 0);
                acc[1][nt] = __builtin_amdgcn_mfma_f32_16x16x32_bf16(hA[1][ks], b, acc[1][nt], 0, 0, 0);
            }
        }

        // A-apply in C-frag regs (verified)
        #pragma unroll
        for (int mt = 0; mt < 2; ++mt)
            #pragma unroll
            for (int nt = 0; nt < 4; ++nt) {
                float own[4], oth[4];
                #pragma unroll
                for (int q = 0; q < 4; ++q) {
                    own[q] = acc[mt][nt][q];
                    oth[q] = __shfl_xor(own[q], 16, 64);
                }
                float yL[4], yH[4];
                #pragma unroll
                for (int q = 0; q < 4; ++q) {
                    yL[q] = half ? oth[q] : own[q];
                    yH[q] = half ? own[q] : oth[q];
                }
                float S = yL[0]+yL[1]+yL[2]+yL[3]+yH[0]+yH[1]+yH[2]+yH[3];
                float o0, o1, o2, o3;
                if (!half) {
                    o0 = (S - yL[0] - yH[1] - yH[2] - yH[3]) * 0.25f;
                    o1 = (S - yL[1] - yH[2] - yH[3]) * 0.2f;
                    o2 = (S - yL[2] - yH[3]) * (1.f/6.f);
                    o3 = (S - yL[3]) * (1.f/7.f);
                } else {
                    o0 = (S - yH[0]) * (1.f/7.f);
                    o1 = (S - yH[1] - yL[0]) * (1.f/6.f);
                    o2 = (S - yH[2] - yL[0] - yL[1]) * 0.2f;
                    o3 = (S - yH[3] - yL[0] - yL[1] - yL[2]) * 0.25f;
                }
                acc[mt][nt][0] = o0; acc[mt][nt][1] = o1;
                acc[mt][nt][2] = o2; acc[mt][nt][3] = o3;
            }

        // add bias (after A-apply, before pass-2 accumulation)
        #pragma unroll
        for (int nt = 0; nt < 4; ++nt) {
            float bv = bl12[lay * 128 + wc * 64 + nt * 16 + lc];
            #pragma unroll
            for (int mt = 0; mt < 2; ++mt)
                #pragma unroll
                for (int q = 0; q < 4; ++q) acc[mt][nt][q] += bv;
        }

        // pass 2: acc += h @ Wr^T  (B from L2)
        #pragma unroll
        for (int ks = 0; ks < 4; ++ks) {
            #pragma unroll
            for (int nt = 0; nt < 4; ++nt) {
                bf16x8 b = *(const bf16x8*)&wrp[((wc * 4 + nt) * 4 + ks) * 512 + l * 8];
                acc[0][nt] = __builtin_amdgcn_mfma_f32_16x16x32_bf16(hA[0][ks], b, acc[0][nt], 0, 0, 0);
                acc[1][nt] = __builtin_amdgcn_mfma_f32_16x16x32_bf16(hA[1][ks], b, acc[1][nt], 0, 0, 0);
            }
        }

        ln_epi(lng + (lay + 1) * 128, lnb + (lay + 1) * 128, true);
    }

    // ---- node mean -> patch features ----
    {
        const int gi = t >> 5, c0 = t & 31;
        #pragma unroll
        for (int k = 0; k < 4; ++k) {
            int c = c0 + 32 * k;
            float s = 0.f;
            #pragma unroll
            for (int j = 0; j < 8; ++j)
                s += bf2f(hT[(gi * 8 + j) * 128 + (c ^ (j << 3))]);
            pf[(size_t)(g0 + gi) * 128 + c] = s * 0.125f;
        }
    }
}

// =====================================================================
// K2: xg1 = pf(63488,128) @ wih1^T + bih1 -> bf16. wB frag-major (stride 512).
// =====================================================================
__global__ __launch_bounds__(256) void k2_xg(
    const float* __restrict__ src, const unsigned short* __restrict__ wB,
    const float* __restrict__ bias, unsigned short* __restrict__ out)
{
    const int t = threadIdx.x, w = t >> 6, l = t & 63;
    const int lc = l & 15, li = l >> 4;
    const int m0 = blockIdx.x * 64 + w * 16;

    bf16x8 aA[4];
    #pragma unroll
    for (int ks = 0; ks < 4; ++ks) {
        const float* p = src + (size_t)(m0 + lc) * 128 + ks * 32 + li * 8;
        float4 f0 = *(const float4*)p;
        float4 f1 = *(const float4*)(p + 4);
        bf16x8 v;
        v[0] = (short)f2bf(f0.x); v[1] = (short)f2bf(f0.y);
        v[2] = (short)f2bf(f0.z); v[3] = (short)f2bf(f0.w);
        v[4] = (short)f2bf(f1.x); v[5] = (short)f2bf(f1.y);
        v[6] = (short)f2bf(f1.z); v[7] = (short)f2bf(f1.w);
        aA[ks] = v;
    }
    #pragma unroll 2
    for (int nt = 0; nt < 24; ++nt) {
        float bv = bias[nt * 16 + lc];
        f32x4 acc = (f32x4){bv, bv, bv, bv};
        #pragma unroll
        for (int ks = 0; ks < 4; ++ks) {
            bf16x8 b = *(const bf16x8*)&wB[(size_t)(nt * 4 + ks) * 512 + l * 8];
            acc = __builtin_amdgcn_mfma_f32_16x16x32_bf16(aA[ks], b, acc, 0, 0, 0);
        }
        #pragma unroll
        for (int q = 0; q < 4; ++q) {
            int m = m0 + li * 4 + q;
            out[(size_t)m * 384 + nt * 16 + lc] = f2bf(acc[q]);
        }
    }
}

// =====================================================================
// K3: both GRU layers fused, 31 steps in-kernel, weights (frag-major) in regs.
// =====================================================================
__global__ __launch_bounds__(512, 2) void k3_gru(
    const unsigned short* __restrict__ xg, const unsigned short* __restrict__ wbf,
    const float* __restrict__ bih, const float* __restrict__ bhh,
    float* __restrict__ gbuf)
{
    __shared__ unsigned short h1S[16][136];
    __shared__ unsigned short h2S[16][136];

    const int t = threadIdx.x, w = t >> 6, l = t & 63;
    const int lc = l & 15, li = l >> 4;
    const int col = w * 16 + lc;          // 0..127
    const int kgrp = li * 8;
    const int b0 = blockIdx.x * 8;
    const bool act = (li < 2);

    for (int i = t; i < 16 * 136; i += 512) {
        ((unsigned short*)h1S)[i] = 0;
        ((unsigned short*)h2S)[i] = 0;
    }

    const unsigned short* wih2 = wbf + 114688;
    const unsigned short* whh1 = wbf + 163840;
    const unsigned short* whh2 = wbf + 212992;
    bf16x8 Wh1[3][4], Wi2[3][4], Wh2[3][4];
    #pragma unroll
    for (int g = 0; g < 3; ++g)
        #pragma unroll
        for (int ks = 0; ks < 4; ++ks) {
            size_t off = (size_t)((g * 8 + w) * 4 + ks) * 512 + l * 8;
            Wh1[g][ks] = *(const bf16x8*)(whh1 + off);
            Wi2[g][ks] = *(const bf16x8*)(wih2 + off);
            Wh2[g][ks] = *(const bf16x8*)(whh2 + off);
        }
    float bh1[3], bi2[3], bh2[3];
    #pragma unroll
    for (int g = 0; g < 3; ++g) {
        bh1[g] = bhh[g * 128 + col];
        bi2[g] = bih[384 + g * 128 + col];
        bh2[g] = bhh[384 + g * 128 + col];
    }

    float h1r[4] = {0.f, 0.f, 0.f, 0.f};
    float h2r[4] = {0.f, 0.f, 0.f, 0.f};
    float x1[3][4];

    if (act) {
        #pragma unroll
        for (int g = 0; g < 3; ++g)
            #pragma unroll
            for (int q = 0; q < 4; ++q)
                x1[g][q] = bf2f(xg[((size_t)(b0 + li * 4 + q) * 31 + 0) * 384 + g * 128 + col]);
    }
    __syncthreads();

    for (int ts = 0; ts < 31; ++ts) {
        bf16x8 aH[4];
        #pragma unroll
        for (int ks = 0; ks < 4; ++ks) aH[ks] = *(const bf16x8*)&h1S[lc][ks * 32 + kgrp];
        f32x4 acc[3];
        #pragma unroll
        for (int g = 0; g < 3; ++g) {
            acc[g] = (f32x4){0.f, 0.f, 0.f, 0.f};
            #pragma unroll
            for (int ks = 0; ks < 4; ++ks)
                acc[g] = __builtin_amdgcn_mfma_f32_16x16x32_bf16(aH[ks], Wh1[g][ks], acc[g], 0, 0, 0);
        }
        float xn[3][4];
        if (act && ts < 30) {
            #pragma unroll
            for (int g = 0; g < 3; ++g)
                #pragma unroll
                for (int q = 0; q < 4; ++q)
                    xn[g][q] = bf2f(xg[((size_t)(b0 + li * 4 + q) * 31 + ts + 1) * 384 + g * 128 + col]);
        }
        if (act) {
            #pragma unroll
            for (int q = 0; q < 4; ++q) {
                float r  = sigm(x1[0][q] + acc[0][q] + bh1[0]);
                float z  = sigm(x1[1][q] + acc[1][q] + bh1[1]);
                float nn = tanh_(x1[2][q] + r * (acc[2][q] + bh1[2]));
                h1r[q] = (1.f - z) * nn + z * h1r[q];
            }
        }
        __syncthreads();
        if (act) {
            #pragma unroll
            for (int q = 0; q < 4; ++q) h1S[li * 4 + q][col] = f2bf(h1r[q]);
        }
        __syncthreads();

        bf16x8 aH1n[4], aH2[4];
        #pragma unroll
        for (int ks = 0; ks < 4; ++ks) {
            aH1n[ks] = *(const bf16x8*)&h1S[lc][ks * 32 + kgrp];
            aH2[ks]  = *(const bf16x8*)&h2S[lc][ks * 32 + kgrp];
        }
        f32x4 ax2[3], ah2[3];
        #pragma unroll
        for (int g = 0; g < 3; ++g) {
            ax2[g] = (f32x4){0.f, 0.f, 0.f, 0.f};
            ah2[g] = (f32x4){0.f, 0.f, 0.f, 0.f};
            #pragma unroll
            for (int ks = 0; ks < 4; ++ks) {
                ax2[g] = __builtin_amdgcn_mfma_f32_16x16x32_bf16(aH1n[ks], Wi2[g][ks], ax2[g], 0, 0, 0);
                ah2[g] = __builtin_amdgcn_mfma_f32_16x16x32_bf16(aH2[ks],  Wh2[g][ks], ah2[g], 0, 0, 0);
            }
        }
        if (act) {
            #pragma unroll
            for (int q = 0; q < 4; ++q) {
                float xr = ax2[0][q] + bi2[0];
                float xz = ax2[1][q] + bi2[1];
                float xn2 = ax2[2][q] + bi2[2];
                float r  = sigm(xr + ah2[0][q] + bh2[0]);
                float z  = sigm(xz + ah2[1][q] + bh2[1]);
                float nn = tanh_(xn2 + r * (ah2[2][q] + bh2[2]));
                h2r[q] = (1.f - z) * nn + z * h2r[q];
            }
        }
        __syncthreads();
        if (act) {
            #pragma unroll
            for (int q = 0; q < 4; ++q) h2S[li * 4 + q][col] = f2bf(h2r[q]);
        }
        __syncthreads();

        #pragma unroll
        for (int g = 0; g < 3; ++g)
            #pragma unroll
            for (int q = 0; q < 4; ++q) x1[g][q] = xn[g][q];
    }

    if (act) {
        #pragma unroll
        for (int q = 0; q < 4; ++q)
            gbuf[(size_t)(b0 + li * 4 + q) * 128 + col] = h2r[q];
    }
}

// =====================================================================
// K4: logits = g(2048,128) @ etf(128,8)
// =====================================================================
__global__ __launch_bounds__(256) void k4_logits(
    const float* __restrict__ g, const float* __restrict__ etf, float* __restrict__ logits)
{
    const int idx = blockIdx.x * 256 + threadIdx.x;
    const int b = idx >> 3, c = idx & 7;
    float s = 0.f;
    #pragma unroll 8
    for (int f = 0; f < 128; ++f) s += g[(size_t)b * 128 + f] * etf[f * 8 + c];
    logits[idx] = s;
}

// =====================================================================
extern "C" void kernel_launch(void* const* d_in, const int* in_sizes, int n_in,
                              void* d_out, int out_size, void* d_ws, size_t ws_size,
                              hipStream_t stream) {
    const float* iq   = (const float*)d_in[0];
    const float* Wl0  = (const float*)d_in[1];
    const float* bl0  = (const float*)d_in[2];
    const float* Wr0  = (const float*)d_in[3];
    const float* Wl12 = (const float*)d_in[4];
    const float* bl12 = (const float*)d_in[5];
    const float* Wr12 = (const float*)d_in[6];
    const float* lng  = (const float*)d_in[7];
    const float* lnb  = (const float*)d_in[8];
    const float* wih  = (const float*)d_in[9];
    const float* whh  = (const float*)d_in[10];
    const float* bih  = (const float*)d_in[11];
    const float* bhh  = (const float*)d_in[12];
    const float* etf  = (const float*)d_in[13];

    float* out    = (float*)d_out;
    float* logits = out;                       // 2048*8
    float* gbuf   = out + 16384;               // 2048*128
    float* pf     = out + 16384 + 262144;      // 63488*128

    // ws: [wbf 266240 u16 = 520KB][xg1 bf16 63488*384 u16 = 48.76MB]
    unsigned short* wbf = (unsigned short*)d_ws;
    unsigned short* xg  = wbf + 266240;

    k0_wconv<<<1040, 256, 0, stream>>>(Wl12, Wr12, wih, whh, Wl0, Wr0, wbf);
    k1_sage<<<7936, 256, 0, stream>>>(iq, bl0, wbf, bl12, lng, lnb, pf);
    k2_xg<<<992, 256, 0, stream>>>(pf, wbf + 65536, bih, xg);
    k3_gru<<<256, 512, 0, stream>>>(xg, wbf, bih, bhh, gbuf);
    k4_logits<<<64, 256, 0, stream>>>(gbuf, etf, logits);
}

// Round 12
// 305.315 us; speedup vs baseline: 1.2024x; 1.0190x over previous
//
#include <hip/hip_runtime.h>
#include <hip/hip_bf16.h>

typedef __attribute__((ext_vector_type(8))) short bf16x8;
typedef __attribute__((ext_vector_type(4))) float f32x4;

// ---------- helpers ----------
__device__ __forceinline__ unsigned short f2bf(float v) {
    union { __hip_bfloat16 h; unsigned short u; } cv;
    cv.h = __float2bfloat16(v);           // hw RNE convert
    return cv.u;
}
__device__ __forceinline__ float bf2f(unsigned short u) {
    return __uint_as_float(((unsigned int)u) << 16);
}
__device__ __forceinline__ float sigm(float x) { return 1.f / (1.f + __expf(-x)); }
__device__ __forceinline__ float tanh_(float x) { return 2.f / (1.f + __expf(-2.f * x)) - 1.f; }
__device__ __forceinline__ float adjW(int i, int j) {
    const float inv[8] = {1.f/4.f, 1.f/5.f, 1.f/6.f, 1.f/7.f,
                          1.f/7.f, 1.f/6.f, 1.f/5.f, 1.f/4.f};
    int d = i - j; d = d < 0 ? -d : d;
    return (d >= 1 && d <= 4) ? inv[i] : 0.f;
}

// DPP 16-lane row reduction (VALU pipe)
template<int CTRL>
__device__ __forceinline__ float dppadd(float v) {
    int d = __builtin_amdgcn_update_dpp(0, __float_as_int(v), CTRL, 0xF, 0xF, true);
    return v + __int_as_float(d);
}
__device__ __forceinline__ float rowsum16(float v) {
    v = dppadd<0xB1>(v);    // quad_perm xor1
    v = dppadd<0x4E>(v);    // quad_perm xor2
    v = dppadd<0x124>(v);   // row_ror:4
    v = dppadd<0x128>(v);   // row_ror:8
    return v;
}

// =====================================================================
// K0: weights -> bf16 FRAGMENT-MAJOR (frag = 512 u16).
// elem (col,k) -> ((col>>4)*4+(k>>5))*512 + ((k>>3)&3)*128 + (col&15)*8 + (k&7)
// u16 layout: [0 Wl12 2x16384][32768 Wr12 2x16384][65536 wih 2x49152]
//             [163840 whh 2x49152][262144 w0frag 4096]
// =====================================================================
__global__ __launch_bounds__(256) void k0_wconv(const float* __restrict__ Wl12,
    const float* __restrict__ Wr12, const float* __restrict__ wih,
    const float* __restrict__ whh, const float* __restrict__ Wl0,
    const float* __restrict__ Wr0, unsigned short* __restrict__ wbf)
{
    int i = blockIdx.x * 256 + threadIdx.x;   // 0..266239
    if (i < 262144) {
        float v; int base, j;
        if (i < 32768)        { v = Wl12[i];        base = (i >> 14) * 16384;           j = i & 16383; }
        else if (i < 65536)   { int s = i - 32768;  v = Wr12[s]; base = 32768 + (s >> 14) * 16384; j = s & 16383; }
        else if (i < 163840)  { int s = i - 65536;  v = wih[s];  base = 65536 + (s / 49152) * 49152; j = s % 49152; }
        else                  { int s = i - 163840; v = whh[s];  base = 163840 + (s / 49152) * 49152; j = s % 49152; }
        int col = j >> 7, k = j & 127;
        int perm = ((col >> 4) * 4 + (k >> 5)) * 512 + ((k >> 3) & 3) * 128 + (col & 15) * 8 + (k & 7);
        wbf[base + perm] = f2bf(v);
    } else {
        int e2 = i - 262144;              // 0..4095
        int ct  = e2 >> 9;
        int off = e2 & 511;
        int li2 = off >> 7;
        int rem = off & 127;
        int colLow = rem >> 3;
        int kLow = off & 7;
        int k = li2 * 8 + kLow;
        int col = ct * 16 + colLow;
        float v = 0.f;
        if (k < 2)      v = Wl0[col * 2 + k];
        else if (k < 4) v = Wr0[col * 2 + k - 2];
        wbf[i] = f2bf(v);
    }
}

// =====================================================================
// K1: fused graph stage, 256 thr (2x2 waves), 8 graphs/block.
// B-frags direct from L2; hT bf16 XOR-swizzled; DPP stats; bias folded
// into acc init (A rows sum to 1 -> bias passes through A-apply).
// =====================================================================
__global__ __launch_bounds__(256, 4) void k1_sage(
    const float* __restrict__ iq,
    const float* __restrict__ bl0,
    const unsigned short* __restrict__ wbf,
    const float* __restrict__ bl12,
    const float* __restrict__ lng, const float* __restrict__ lnb,
    float* __restrict__ pf)
{
    __shared__ unsigned short hT[64 * 128];      // 16 KB
    __shared__ float statS[64][4];
    __shared__ float xS[64][2], axS[64][2];

    const int t  = threadIdx.x;
    const int l  = t & 63;
    const int w  = t >> 6;
    const int wr = w >> 1, wc = w & 1;
    const int lc = l & 15, li = l >> 4;
    const int kgrp = li * 8;
    const int half = li & 1;
    const int g0 = blockIdx.x * 8;

    // ---- patchify ----
    if (t < 128) {
        int r = t >> 1, c = t & 1;
        int gid = g0 + (r >> 3);
        int node = r & 7;
        int b = gid / 31, p = gid - b * 31;
        xS[r][c] = iq[((size_t)b * 2 + c) * 128 + p * 4 + node];
    }
    __syncthreads();
    if (t < 128) {
        int r = t >> 1, c = t & 1;
        int node = r & 7, base = r & ~7;
        float s = 0.f;
        #pragma unroll
        for (int j = 0; j < 8; ++j) s += adjW(node, j) * xS[base + j][c];
        axS[r][c] = s;
    }
    __syncthreads();

    f32x4 acc[2][4];

    // LN epilogue: vector stats + DPP + coef-form normalize (+residual RMW)
    auto ln_epi = [&](const float* gptr, const float* btptr, bool resid) {
        float rs[2][4], rq[2][4];
        #pragma unroll
        for (int mt = 0; mt < 2; ++mt) {
            f32x4 sv = (acc[mt][0] + acc[mt][1]) + (acc[mt][2] + acc[mt][3]);
            f32x4 qv = acc[mt][0] * acc[mt][0] + acc[mt][1] * acc[mt][1]
                     + acc[mt][2] * acc[mt][2] + acc[mt][3] * acc[mt][3];
            #pragma unroll
            for (int q = 0; q < 4; ++q) {
                rs[mt][q] = rowsum16(sv[q]);
                rq[mt][q] = rowsum16(qv[q]);
            }
        }
        if (lc == 0) {
            #pragma unroll
            for (int mt = 0; mt < 2; ++mt)
                #pragma unroll
                for (int q = 0; q < 4; ++q) {
                    int row = wr * 32 + mt * 16 + li * 4 + q;
                    statS[row][wc * 2]     = rs[mt][q];
                    statS[row][wc * 2 + 1] = rq[mt][q];
                }
        }
        __syncthreads();
        float gam[4], bet[4];
        #pragma unroll
        for (int nt = 0; nt < 4; ++nt) {
            int col = wc * 64 + nt * 16 + lc;
            gam[nt] = gptr[col]; bet[nt] = btptr[col];
        }
        #pragma unroll
        for (int mt = 0; mt < 2; ++mt)
            #pragma unroll
            for (int q = 0; q < 4; ++q) {
                int row = wr * 32 + mt * 16 + li * 4 + q;
                int s8 = (row & 7) << 3;
                float4 st = *(const float4*)&statS[row][0];
                float sum = st.x + st.z, sq = st.y + st.w;
                float mu   = sum * (1.f / 128.f);
                float var  = sq * (1.f / 128.f) - mu * mu;
                float rstd = rsqrtf(var + 1e-5f);
                #pragma unroll
                for (int nt = 0; nt < 4; ++nt) {
                    int col = wc * 64 + nt * 16 + lc;
                    int idx = row * 128 + (col ^ s8);
                    float ag = rstd * gam[nt];
                    float bg = __builtin_fmaf(-mu, ag, bet[nt]);
                    float v  = fmaxf(__builtin_fmaf(acc[mt][nt][q], ag, bg), 0.f);
                    float hn = resid ? (bf2f(hT[idx]) + v) : v;
                    hT[idx] = f2bf(hn);
                }
            }
        __syncthreads();
    };

    // ---- layer 0 via MFMA: A = [agg_x | x] (K=4 in 32), bias in acc init ----
    {
        bf16x8 xA[2];
        #pragma unroll
        for (int mt = 0; mt < 2; ++mt) {
            bf16x8 v = (bf16x8){0, 0, 0, 0, 0, 0, 0, 0};
            if (li == 0) {
                int row = wr * 32 + mt * 16 + lc;
                v[0] = (short)f2bf(axS[row][0]); v[1] = (short)f2bf(axS[row][1]);
                v[2] = (short)f2bf(xS[row][0]);  v[3] = (short)f2bf(xS[row][1]);
            }
            xA[mt] = v;
        }
        const unsigned short* w0f = wbf + 262144;
        #pragma unroll
        for (int nt = 0; nt < 4; ++nt) {
            float bv = bl0[wc * 64 + nt * 16 + lc];
            acc[0][nt] = (f32x4){bv, bv, bv, bv};
            acc[1][nt] = (f32x4){bv, bv, bv, bv};
        }
        #pragma unroll
        for (int nt = 0; nt < 4; ++nt) {
            bf16x8 b0 = *(const bf16x8*)&w0f[(wc * 4 + nt) * 512 + l * 8];
            acc[0][nt] = __builtin_amdgcn_mfma_f32_16x16x32_bf16(xA[0], b0, acc[0][nt], 0, 0, 0);
            acc[1][nt] = __builtin_amdgcn_mfma_f32_16x16x32_bf16(xA[1], b0, acc[1][nt], 0, 0, 0);
        }
        ln_epi(lng, lnb, false);
    }

    // ---- layers 1,2 ----
    const int aswz = (lc & 7) << 3;
    #pragma unroll 1
    for (int lay = 0; lay < 2; ++lay) {
        bf16x8 hA[2][4];
        #pragma unroll
        for (int mt = 0; mt < 2; ++mt)
            #pragma unroll
            for (int ks = 0; ks < 4; ++ks) {
                int row = wr * 32 + 16 * mt + lc;
                hA[mt][ks] = *(const bf16x8*)&hT[row * 128 + ((ks * 32 + kgrp) ^ aswz)];
            }

        const unsigned short* wl  = wbf + lay * 16384;
        const unsigned short* wrp = wbf + 32768 + lay * 16384;

        // bias folded into acc init: A@(Y1+b) = A@Y1 + b since A rows sum to 1
        #pragma unroll
        for (int nt = 0; nt < 4; ++nt) {
            float bv = bl12[lay * 128 + wc * 64 + nt * 16 + lc];
            acc[0][nt] = (f32x4){bv, bv, bv, bv};
            acc[1][nt] = (f32x4){bv, bv, bv, bv};
        }

        // pass 1: acc = bias + h @ Wl^T
        #pragma unroll
        for (int ks = 0; ks < 4; ++ks) {
            #pragma unroll
            for (int nt = 0; nt < 4; ++nt) {
                bf16x8 b = *(const bf16x8*)&wl[((wc * 4 + nt) * 4 + ks) * 512 + l * 8];
                acc[0][nt] = __builtin_amdgcn_mfma_f32_16x16x32_bf16(hA[0][ks], b, acc[0][nt], 0, 0, 0);
                acc[1][nt] = __builtin_amdgcn_mfma_f32_16x16x32_bf16(hA[1][ks], b, acc[1][nt], 0, 0, 0);
            }
        }

        // A-apply in C-frag regs (verified)
        #pragma unroll
        for (int mt = 0; mt < 2; ++mt)
            #pragma unroll
            for (int nt = 0; nt < 4; ++nt) {
                float own[4], oth[4];
                #pragma unroll
                for (int q = 0; q < 4; ++q) {
                    own[q] = acc[mt][nt][q];
                    oth[q] = __shfl_xor(own[q], 16, 64);
                }
                float yL[4], yH[4];
                #pragma unroll
                for (int q = 0; q < 4; ++q) {
                    yL[q] = half ? oth[q] : own[q];
                    yH[q] = half ? own[q] : oth[q];
                }
                float S = yL[0]+yL[1]+yL[2]+yL[3]+yH[0]+yH[1]+yH[2]+yH[3];
                float o0, o1, o2, o3;
                if (!half) {
                    o0 = (S - yL[0] - yH[1] - yH[2] - yH[3]) * 0.25f;
                    o1 = (S - yL[1] - yH[2] - yH[3]) * 0.2f;
                    o2 = (S - yL[2] - yH[3]) * (1.f/6.f);
                    o3 = (S - yL[3]) * (1.f/7.f);
                } else {
                    o0 = (S - yH[0]) * (1.f/7.f);
                    o1 = (S - yH[1] - yL[0]) * (1.f/6.f);
                    o2 = (S - yH[2] - yL[0] - yL[1]) * 0.2f;
                    o3 = (S - yH[3] - yL[0] - yL[1] - yL[2]) * 0.25f;
                }
                acc[mt][nt][0] = o0; acc[mt][nt][1] = o1;
                acc[mt][nt][2] = o2; acc[mt][nt][3] = o3;
            }

        // pass 2: acc += h @ Wr^T
        #pragma unroll
        for (int ks = 0; ks < 4; ++ks) {
            #pragma unroll
            for (int nt = 0; nt < 4; ++nt) {
                bf16x8 b = *(const bf16x8*)&wrp[((wc * 4 + nt) * 4 + ks) * 512 + l * 8];
                acc[0][nt] = __builtin_amdgcn_mfma_f32_16x16x32_bf16(hA[0][ks], b, acc[0][nt], 0, 0, 0);
                acc[1][nt] = __builtin_amdgcn_mfma_f32_16x16x32_bf16(hA[1][ks], b, acc[1][nt], 0, 0, 0);
            }
        }

        ln_epi(lng + (lay + 1) * 128, lnb + (lay + 1) * 128, true);
    }

    // ---- node mean -> patch features ----
    {
        const int gi = t >> 5, c0 = t & 31;
        #pragma unroll
        for (int k = 0; k < 4; ++k) {
            int c = c0 + 32 * k;
            float s = 0.f;
            #pragma unroll
            for (int j = 0; j < 8; ++j)
                s += bf2f(hT[(gi * 8 + j) * 128 + (c ^ (j << 3))]);
            pf[(size_t)(g0 + gi) * 128 + c] = s * 0.125f;
        }
    }
}

// =====================================================================
// K2: xg1 = pf(63488,128) @ wih1^T + bih1 -> bf16. wB frag-major.
// =====================================================================
__global__ __launch_bounds__(256) void k2_xg(
    const float* __restrict__ src, const unsigned short* __restrict__ wB,
    const float* __restrict__ bias, unsigned short* __restrict__ out)
{
    const int t = threadIdx.x, w = t >> 6, l = t & 63;
    const int lc = l & 15, li = l >> 4;
    const int m0 = blockIdx.x * 64 + w * 16;

    bf16x8 aA[4];
    #pragma unroll
    for (int ks = 0; ks < 4; ++ks) {
        const float* p = src + (size_t)(m0 + lc) * 128 + ks * 32 + li * 8;
        float4 f0 = *(const float4*)p;
        float4 f1 = *(const float4*)(p + 4);
        bf16x8 v;
        v[0] = (short)f2bf(f0.x); v[1] = (short)f2bf(f0.y);
        v[2] = (short)f2bf(f0.z); v[3] = (short)f2bf(f0.w);
        v[4] = (short)f2bf(f1.x); v[5] = (short)f2bf(f1.y);
        v[6] = (short)f2bf(f1.z); v[7] = (short)f2bf(f1.w);
        aA[ks] = v;
    }
    #pragma unroll 2
    for (int nt = 0; nt < 24; ++nt) {
        float bv = bias[nt * 16 + lc];
        f32x4 acc = (f32x4){bv, bv, bv, bv};
        #pragma unroll
        for (int ks = 0; ks < 4; ++ks) {
            bf16x8 b = *(const bf16x8*)&wB[(size_t)(nt * 4 + ks) * 512 + l * 8];
            acc = __builtin_amdgcn_mfma_f32_16x16x32_bf16(aA[ks], b, acc, 0, 0, 0);
        }
        #pragma unroll
        for (int q = 0; q < 4; ++q) {
            int m = m0 + li * 4 + q;
            out[(size_t)m * 384 + nt * 16 + lc] = f2bf(acc[q]);
        }
    }
}

// =====================================================================
// K3: both GRU layers fused + final logits. 31 steps in-kernel.
// =====================================================================
__global__ __launch_bounds__(512, 2) void k3_gru(
    const unsigned short* __restrict__ xg, const unsigned short* __restrict__ wbf,
    const float* __restrict__ bih, const float* __restrict__ bhh,
    const float* __restrict__ etf,
    float* __restrict__ gbuf, float* __restrict__ logits)
{
    __shared__ unsigned short h1S[16][136];
    __shared__ unsigned short h2S[16][136];

    const int t = threadIdx.x, w = t >> 6, l = t & 63;
    const int lc = l & 15, li = l >> 4;
    const int col = w * 16 + lc;          // 0..127
    const int kgrp = li * 8;
    const int b0 = blockIdx.x * 8;
    const bool act = (li < 2);

    for (int i = t; i < 16 * 136; i += 512) {
        ((unsigned short*)h1S)[i] = 0;
        ((unsigned short*)h2S)[i] = 0;
    }

    const unsigned short* wih2 = wbf + 114688;
    const unsigned short* whh1 = wbf + 163840;
    const unsigned short* whh2 = wbf + 212992;
    bf16x8 Wh1[3][4], Wi2[3][4], Wh2[3][4];
    #pragma unroll
    for (int g = 0; g < 3; ++g)
        #pragma unroll
        for (int ks = 0; ks < 4; ++ks) {
            size_t off = (size_t)((g * 8 + w) * 4 + ks) * 512 + l * 8;
            Wh1[g][ks] = *(const bf16x8*)(whh1 + off);
            Wi2[g][ks] = *(const bf16x8*)(wih2 + off);
            Wh2[g][ks] = *(const bf16x8*)(whh2 + off);
        }
    float bh1[3], bi2[3], bh2[3];
    #pragma unroll
    for (int g = 0; g < 3; ++g) {
        bh1[g] = bhh[g * 128 + col];
        bi2[g] = bih[384 + g * 128 + col];
        bh2[g] = bhh[384 + g * 128 + col];
    }

    float h1r[4] = {0.f, 0.f, 0.f, 0.f};
    float h2r[4] = {0.f, 0.f, 0.f, 0.f};
    float x1[3][4];

    if (act) {
        #pragma unroll
        for (int g = 0; g < 3; ++g)
            #pragma unroll
            for (int q = 0; q < 4; ++q)
                x1[g][q] = bf2f(xg[((size_t)(b0 + li * 4 + q) * 31 + 0) * 384 + g * 128 + col]);
    }
    __syncthreads();

    for (int ts = 0; ts < 31; ++ts) {
        bf16x8 aH[4];
        #pragma unroll
        for (int ks = 0; ks < 4; ++ks) aH[ks] = *(const bf16x8*)&h1S[lc][ks * 32 + kgrp];
        f32x4 acc[3];
        #pragma unroll
        for (int g = 0; g < 3; ++g) {
            acc[g] = (f32x4){0.f, 0.f, 0.f, 0.f};
            #pragma unroll
            for (int ks = 0; ks < 4; ++ks)
                acc[g] = __builtin_amdgcn_mfma_f32_16x16x32_bf16(aH[ks], Wh1[g][ks], acc[g], 0, 0, 0);
        }
        float xn[3][4];
        if (act && ts < 30) {
            #pragma unroll
            for (int g = 0; g < 3; ++g)
                #pragma unroll
                for (int q = 0; q < 4; ++q)
                    xn[g][q] = bf2f(xg[((size_t)(b0 + li * 4 + q) * 31 + ts + 1) * 384 + g * 128 + col]);
        }
        if (act) {
            #pragma unroll
            for (int q = 0; q < 4; ++q) {
                float r  = sigm(x1[0][q] + acc[0][q] + bh1[0]);
                float z  = sigm(x1[1][q] + acc[1][q] + bh1[1]);
                float nn = tanh_(x1[2][q] + r * (acc[2][q] + bh1[2]));
                h1r[q] = (1.f - z) * nn + z * h1r[q];
            }
        }
        __syncthreads();
        if (act) {
            #pragma unroll
            for (int q = 0; q < 4; ++q) h1S[li * 4 + q][col] = f2bf(h1r[q]);
        }
        __syncthreads();

        bf16x8 aH1n[4], aH2[4];
        #pragma unroll
        for (int ks = 0; ks < 4; ++ks) {
            aH1n[ks] = *(const bf16x8*)&h1S[lc][ks * 32 + kgrp];
            aH2[ks]  = *(const bf16x8*)&h2S[lc][ks * 32 + kgrp];
        }
        f32x4 ax2[3], ah2[3];
        #pragma unroll
        for (int g = 0; g < 3; ++g) {
            ax2[g] = (f32x4){0.f, 0.f, 0.f, 0.f};
            ah2[g] = (f32x4){0.f, 0.f, 0.f, 0.f};
            #pragma unroll
            for (int ks = 0; ks < 4; ++ks) {
                ax2[g] = __builtin_amdgcn_mfma_f32_16x16x32_bf16(aH1n[ks], Wi2[g][ks], ax2[g], 0, 0, 0);
                ah2[g] = __builtin_amdgcn_mfma_f32_16x16x32_bf16(aH2[ks],  Wh2[g][ks], ah2[g], 0, 0, 0);
            }
        }
        if (act) {
            #pragma unroll
            for (int q = 0; q < 4; ++q) {
                float xr = ax2[0][q] + bi2[0];
                float xz = ax2[1][q] + bi2[1];
                float xn2 = ax2[2][q] + bi2[2];
                float r  = sigm(xr + ah2[0][q] + bh2[0]);
                float z  = sigm(xz + ah2[1][q] + bh2[1]);
                float nn = tanh_(xn2 + r * (ah2[2][q] + bh2[2]));
                h2r[q] = (1.f - z) * nn + z * h2r[q];
            }
        }
        __syncthreads();
        if (act) {
            #pragma unroll
            for (int q = 0; q < 4; ++q) h2S[li * 4 + q][col] = f2bf(h2r[q]);
        }
        __syncthreads();

        #pragma unroll
        for (int g = 0; g < 3; ++g)
            #pragma unroll
            for (int q = 0; q < 4; ++q) x1[g][q] = xn[g][q];
    }

    if (act) {
        #pragma unroll
        for (int q = 0; q < 4; ++q)
            gbuf[(size_t)(b0 + li * 4 + q) * 128 + col] = h2r[q];
    }

    // ---- fused logits: stage h2 fp32 into reused h1S space, dot with etf ----
    float* fS = (float*)&h1S[0][0];      // 8*128 floats = 4 KB <= 4.25 KB
    __syncthreads();                      // h1S no longer needed
    if (act) {
        #pragma unroll
        for (int q = 0; q < 4; ++q) fS[(li * 4 + q) * 128 + col] = h2r[q];
    }
    __syncthreads();
    if (t < 64) {
        int row = t >> 3, c = t & 7;
        float s = 0.f;
        #pragma unroll 8
        for (int f = 0; f < 128; ++f) s += fS[row * 128 + f] * etf[f * 8 + c];
        logits[(size_t)(b0 + row) * 8 + c] = s;
    }
}

// =====================================================================
extern "C" void kernel_launch(void* const* d_in, const int* in_sizes, int n_in,
                              void* d_out, int out_size, void* d_ws, size_t ws_size,
                              hipStream_t stream) {
    const float* iq   = (const float*)d_in[0];
    const float* Wl0  = (const float*)d_in[1];
    const float* bl0  = (const float*)d_in[2];
    const float* Wr0  = (const float*)d_in[3];
    const float* Wl12 = (const float*)d_in[4];
    const float* bl12 = (const float*)d_in[5];
    const float* Wr12 = (const float*)d_in[6];
    const float* lng  = (const float*)d_in[7];
    const float* lnb  = (const float*)d_in[8];
    const float* wih  = (const float*)d_in[9];
    const float* whh  = (const float*)d_in[10];
    const float* bih  = (const float*)d_in[11];
    const float* bhh  = (const float*)d_in[12];
    const float* etf  = (const float*)d_in[13];

    float* out    = (float*)d_out;
    float* logits = out;                       // 2048*8
    float* gbuf   = out + 16384;               // 2048*128
    float* pf     = out + 16384 + 262144;      // 63488*128

    // ws: [wbf 266240 u16 = 520KB][xg1 bf16 63488*384 u16 = 48.76MB]
    unsigned short* wbf = (unsigned short*)d_ws;
    unsigned short* xg  = wbf + 266240;

    k0_wconv<<<1040, 256, 0, stream>>>(Wl12, Wr12, wih, whh, Wl0, Wr0, wbf);
    k1_sage<<<7936, 256, 0, stream>>>(iq, bl0, wbf, bl12, lng, lnb, pf);
    k2_xg<<<992, 256, 0, stream>>>(pf, wbf + 65536, bih, xg);
    k3_gru<<<256, 512, 0, stream>>>(xg, wbf, bih, bhh, etf, gbuf, logits);
}